// Round 6
// baseline (294.831 us; speedup 1.0000x reference)
//
#include <hip/hip_runtime.h>

#define NCOL 64
#define KDIM 128
#define NB 512          // max coarse buckets (dst>>8, N<=131072)
#define CH 2048         // edges per partition chunk

typedef short bf16x8 __attribute__((ext_vector_type(8)));
typedef float f32x4 __attribute__((ext_vector_type(4)));

__device__ __forceinline__ unsigned short f2bf(float f) {
    unsigned int u = __float_as_uint(f);
    return (unsigned short)((u + 0x7fffu + ((u >> 16) & 1u)) >> 16);
}
__device__ __forceinline__ float bflo(unsigned int u) { return __uint_as_float(u << 16); }
__device__ __forceinline__ float bfhi(unsigned int u) { return __uint_as_float(u & 0xffff0000u); }

// ---------------- K1: coarse bucket hist (LDS) + outcnt hist ----------------
__global__ __launch_bounds__(256) void coarse_hist(const int* __restrict__ src,
                                                   const int* __restrict__ dst,
                                                   int* __restrict__ outcnt,
                                                   int* __restrict__ bcnt, int E) {
    __shared__ int lh[NB];
    int tid = threadIdx.x;
    for (int i = tid; i < NB; i += 256) lh[i] = 0;
    __syncthreads();
    int i = blockIdx.x * blockDim.x + tid;
    int stride = gridDim.x * blockDim.x;
    for (int e = i; e < E; e += stride) {
        atomicAdd(&outcnt[src[e]], 1);
        atomicAdd(&lh[dst[e] >> 8], 1);
    }
    __syncthreads();
    for (int k = tid; k < NB; k += 256) {
        int c = lh[k];
        if (c) atomicAdd(&bcnt[k], c);
    }
}

// ---------------- K2: scan bucket counts -> bbase, bcur ----------------
__global__ __launch_bounds__(256) void bucket_scan(const int* __restrict__ bcnt,
                                                   int* __restrict__ bbase, int* __restrict__ bcur,
                                                   int* __restrict__ row_start, int N, int E) {
    __shared__ int wsum[8];
    int tid = threadIdx.x, lane = tid & 63, wv = tid >> 6;
    int a = bcnt[tid], b = bcnt[tid + 256];
    int ia = a, ib = b;
#pragma unroll
    for (int off = 1; off < 64; off <<= 1) {
        int t = __shfl_up(ia, off); if (lane >= off) ia += t;
        int u = __shfl_up(ib, off); if (lane >= off) ib += u;
    }
    if (lane == 63) { wsum[wv] = ia; wsum[4 + wv] = ib; }
    __syncthreads();
    if (tid == 0) { int run = 0; for (int i = 0; i < 8; ++i) { int t = wsum[i]; wsum[i] = run; run += t; } }
    __syncthreads();
    int ea = wsum[wv] + ia - a;
    int eb = wsum[4 + wv] + ib - b;
    bbase[tid] = ea; bcur[tid] = ea;
    bbase[tid + 256] = eb; bcur[tid + 256] = eb;
    if (tid == 0) row_start[N] = E;
}

// ---------------- K3: partition edges into coarse buckets (coalesced writes) ----------------
__global__ __launch_bounds__(256) void partition_kernel(
    const int* __restrict__ src, const int* __restrict__ dst,
    int* __restrict__ bcur, uint2* __restrict__ pairs, int E) {
    __shared__ int hist[NB];
    __shared__ int lbase[NB];
    __shared__ int gbase[NB];
    __shared__ int lcur[NB];
    __shared__ uint2 sp[CH];   // 16 KB
    __shared__ int wsum[8];

    int tid = threadIdx.x, lane = tid & 63, wv = tid >> 6;
    int c0 = blockIdx.x * CH;
    int cnt = min(CH, E - c0);

    for (int i = tid; i < NB; i += 256) hist[i] = 0;
    __syncthreads();
    for (int i = tid; i < cnt; i += 256)
        atomicAdd(&hist[dst[c0 + i] >> 8], 1);
    __syncthreads();

    // exclusive scan of hist[0..511] with 256 threads
    {
        int a = hist[tid], b = hist[tid + 256];
        int ia = a, ib = b;
#pragma unroll
        for (int off = 1; off < 64; off <<= 1) {
            int t = __shfl_up(ia, off); if (lane >= off) ia += t;
            int u = __shfl_up(ib, off); if (lane >= off) ib += u;
        }
        if (lane == 63) { wsum[wv] = ia; wsum[4 + wv] = ib; }
        __syncthreads();
        if (tid == 0) { int run = 0; for (int i = 0; i < 8; ++i) { int t = wsum[i]; wsum[i] = run; run += t; } }
        __syncthreads();
        lbase[tid] = wsum[wv] + ia - a;
        lbase[tid + 256] = wsum[4 + wv] + ib - b;
    }
    __syncthreads();

    // reserve global space per bucket; init local cursors
    for (int k = tid; k < NB; k += 256) {
        int c = hist[k];
        gbase[k] = c ? atomicAdd(&bcur[k], c) : 0;
        lcur[k] = lbase[k];
    }
    __syncthreads();

    // rescatter chunk into bucket-ordered LDS (re-read global, L2-hot)
    for (int i = tid; i < cnt; i += 256) {
        int s = src[c0 + i], d = dst[c0 + i];
        int p = atomicAdd(&lcur[d >> 8], 1);
        sp[p] = make_uint2((unsigned)s, (unsigned)d);
    }
    __syncthreads();

    // linear write-out: consecutive i within a bucket -> consecutive global addrs
    for (int i = tid; i < cnt; i += 256) {
        uint2 p = sp[i];
        int k = (int)(p.y >> 8);
        pairs[gbase[k] + (i - lbase[k])] = p;
    }
}

// ---------------- K4: fine counting sort within bucket -> ssrc + row_start ----------------
__global__ __launch_bounds__(256) void fine_kernel(
    const uint2* __restrict__ pairs, const int* __restrict__ bbase,
    int* __restrict__ row_start, int* __restrict__ ssrc, int E, int nbuck, int N) {
    __shared__ int hist[256];
    __shared__ int cur[256];
    __shared__ int wsum[4];
    int k = blockIdx.x;
    int tid = threadIdx.x, lane = tid & 63, wv = tid >> 6;
    int b0 = bbase[k];
    int b1 = (k + 1 < nbuck) ? bbase[k + 1] : E;

    hist[tid] = 0;
    __syncthreads();
    for (int i = b0 + tid; i < b1; i += 256)
        atomicAdd(&hist[pairs[i].y & 255], 1);
    __syncthreads();

    // exclusive scan of 256
    int x = hist[tid], inc = x;
#pragma unroll
    for (int off = 1; off < 64; off <<= 1) {
        int t = __shfl_up(inc, off); if (lane >= off) inc += t;
    }
    if (lane == 63) wsum[wv] = inc;
    __syncthreads();
    if (tid == 0) { int run = 0; for (int i = 0; i < 4; ++i) { int t = wsum[i]; wsum[i] = run; run += t; } }
    __syncthreads();
    int excl = wsum[wv] + inc - x;

    int d = (k << 8) + tid;
    if (d < N) row_start[d] = b0 + excl;
    cur[tid] = b0 + excl;
    __syncthreads();

    for (int i = b0 + tid; i < b1; i += 256) {
        uint2 p = pairs[i];
        int pos = atomicAdd(&cur[p.y & 255], 1);
        ssrc[pos] = (int)p.x;
    }
}

// ---------------- K5: MFMA dual GEMM ----------------
__global__ __launch_bounds__(256) void matmul_mfma(
    const float* __restrict__ feat, const float* __restrict__ W,
    const float* __restrict__ RW, const float* __restrict__ res_b,
    const int* __restrict__ outcnt,
    unsigned short* __restrict__ hb, float* __restrict__ y, int N) {
    __shared__ bf16x8 Bf[2048];   // 32 KB
    int tid = threadIdx.x;
    for (int idx = tid; idx < 2048; idx += 256) {
        int mat = idx >> 10;
        int kc = (idx >> 8) & 3;
        int ct = (idx >> 6) & 3;
        int l = idx & 63;
        const float* Wp = mat ? RW : W;
        int kbase = kc * 32 + (l >> 4) * 8;
        int col = ct * 16 + (l & 15);
        bf16x8 t;
#pragma unroll
        for (int j = 0; j < 8; ++j)
            t[j] = (short)f2bf(Wp[(size_t)(kbase + j) * NCOL + col]);
        Bf[idx] = t;
    }
    __syncthreads();

    int lane = tid & 63;
    int wid = tid >> 6;
    int wave = blockIdx.x * 4 + wid;
    int nwaves = gridDim.x * 4;
    int ntiles = (N + 15) >> 4;
    int c16 = lane & 15, kg = lane >> 4;

    float rbv[4];
#pragma unroll
    for (int ct = 0; ct < 4; ++ct) rbv[ct] = res_b[ct * 16 + c16];

    for (int tile = wave; tile < ntiles; tile += nwaves) {
        int tb = tile << 4;
        f32x4 acch[4], accr[4];
#pragma unroll
        for (int ct = 0; ct < 4; ++ct) {
            acch[ct] = (f32x4){0.f, 0.f, 0.f, 0.f};
            accr[ct] = (f32x4){0.f, 0.f, 0.f, 0.f};
        }

        int arow = tb + c16; if (arow >= N) arow = N - 1;
        const float* fp = feat + (size_t)arow * KDIM + kg * 8;
#pragma unroll
        for (int kc = 0; kc < 4; ++kc) {
            float4 a0 = *(const float4*)(fp + kc * 32);
            float4 a1 = *(const float4*)(fp + kc * 32 + 4);
            bf16x8 af;
            af[0] = (short)f2bf(a0.x); af[1] = (short)f2bf(a0.y);
            af[2] = (short)f2bf(a0.z); af[3] = (short)f2bf(a0.w);
            af[4] = (short)f2bf(a1.x); af[5] = (short)f2bf(a1.y);
            af[6] = (short)f2bf(a1.z); af[7] = (short)f2bf(a1.w);
#pragma unroll
            for (int ct = 0; ct < 4; ++ct) {
                acch[ct] = __builtin_amdgcn_mfma_f32_16x16x32_bf16(
                    af, Bf[(kc * 4 + ct) * 64 + lane], acch[ct], 0, 0, 0);
                accr[ct] = __builtin_amdgcn_mfma_f32_16x16x32_bf16(
                    af, Bf[1024 + (kc * 4 + ct) * 64 + lane], accr[ct], 0, 0, 0);
            }
        }

        float nrm[4];
#pragma unroll
        for (int r = 0; r < 4; ++r) {
            int rw = tb + kg * 4 + r; if (rw >= N) rw = N - 1;
            nrm[r] = rsqrtf(fmaxf((float)outcnt[rw], 1.0f));
        }
#pragma unroll
        for (int ct = 0; ct < 4; ++ct) {
#pragma unroll
            for (int r = 0; r < 4; ++r) {
                int row = tb + kg * 4 + r;
                if (row < N) {
                    size_t off = (size_t)row * NCOL + ct * 16 + c16;
                    hb[off] = f2bf(acch[ct][r] * nrm[r]);
                    y[off] = fmaxf(accr[ct][r] + rbv[ct], 0.0f);
                }
            }
        }
    }
}

// ---------------- K6: gather, col-pair per lane ----------------
// Wave: half = lane>>5 (edge parity), cp = lane&31 (u32 col-pair of the 128B row).
// Per 2 edges: 1 dword load/lane (one L2 line per edge), 2 unpack + 2 add.
// Row reduce = single shfl_xor(32). Lanes 0..31 write float2, keep BN partials.
__global__ __launch_bounds__(256) void gather_kernel(
    const int* __restrict__ row_start, const int* __restrict__ ssrc,
    const unsigned int* __restrict__ hbu, const float* __restrict__ b,
    float* __restrict__ y, float* __restrict__ stats, int N) {
    int tid = threadIdx.x, lane = tid & 63, wid = tid >> 6;
    int half = lane >> 5;
    int cp = lane & 31;
    int wave = blockIdx.x * 4 + wid;
    int nwaves = gridDim.x * 4;

    float bc0 = b[2 * cp], bc1 = b[2 * cp + 1];
    float bnsum0 = 0.f, bnsum1 = 0.f, bnsq0 = 0.f, bnsq1 = 0.f;

    for (int d = wave; d < N; d += nwaves) {
        int s0 = row_start[d], s1 = row_start[d + 1];
        float acc0 = 0.f, acc1 = 0.f;

        int base = s0;
        for (; base + 8 <= s1; base += 8) {
            int iA = ssrc[base + half];
            int iB = ssrc[base + 2 + half];
            int iC = ssrc[base + 4 + half];
            int iD = ssrc[base + 6 + half];
            unsigned int vA = hbu[(size_t)iA * 32 + cp];
            unsigned int vB = hbu[(size_t)iB * 32 + cp];
            unsigned int vC = hbu[(size_t)iC * 32 + cp];
            unsigned int vD = hbu[(size_t)iD * 32 + cp];
            acc0 += bflo(vA); acc1 += bfhi(vA);
            acc0 += bflo(vB); acc1 += bfhi(vB);
            acc0 += bflo(vC); acc1 += bfhi(vC);
            acc0 += bflo(vD); acc1 += bfhi(vD);
        }
        for (; base < s1; base += 2) {
            int e = base + half;
            if (e < s1) {
                unsigned int v = hbu[(size_t)ssrc[e] * 32 + cp];
                acc0 += bflo(v); acc1 += bfhi(v);
            }
        }

        acc0 += __shfl_xor(acc0, 32);
        acc1 += __shfl_xor(acc1, 32);

        if (lane < 32) {
            float nd = rsqrtf(fmaxf((float)(s1 - s0), 1.0f));
            float* yp = &y[(size_t)d * NCOL + 2 * cp];
            float2 r = *(const float2*)yp;
            float v0 = fmaxf(acc0 * nd + bc0, 0.f) + r.x;
            float v1 = fmaxf(acc1 * nd + bc1, 0.f) + r.y;
            *(float2*)yp = make_float2(v0, v1);
            bnsum0 += v0; bnsum1 += v1;
            bnsq0 += v0 * v0; bnsq1 += v1 * v1;
        }
    }

    __shared__ float bnred[4][128];
    if (lane < 32) {
        bnred[wid][2 * cp] = bnsum0;
        bnred[wid][2 * cp + 1] = bnsum1;
        bnred[wid][64 + 2 * cp] = bnsq0;
        bnred[wid][64 + 2 * cp + 1] = bnsq1;
    }
    __syncthreads();
    if (tid < 128) {
        float v = bnred[0][tid] + bnred[1][tid] + bnred[2][tid] + bnred[3][tid];
        unsafeAtomicAdd(&stats[tid], v);
    }
}

// ---------------- K7: BN scale/shift ----------------
__global__ void bnparam_kernel(const float* __restrict__ gamma, const float* __restrict__ beta,
                               float* __restrict__ stats, float invN) {
    int c = threadIdx.x;
    float mean = stats[c] * invN;
    float var = stats[64 + c] * invN - mean * mean;
    float s = gamma[c] * rsqrtf(var + 1e-5f);
    stats[128 + c] = s;
    stats[192 + c] = beta[c] - mean * s;
}

// ---------------- K8: BN apply (in place, float4) ----------------
__global__ __launch_bounds__(256) void apply_kernel(float* __restrict__ y,
                                                    const float* __restrict__ stats, int total4) {
    int i = blockIdx.x * blockDim.x + threadIdx.x;
    int stride = gridDim.x * blockDim.x;
    float4* y4 = (float4*)y;
    for (; i < total4; i += stride) {
        float4 v = y4[i];
        int cbase = (i & 15) << 2;
        float4 s = *(const float4*)&stats[128 + cbase];
        float4 t = *(const float4*)&stats[192 + cbase];
        v.x = v.x * s.x + t.x;
        v.y = v.y * s.y + t.y;
        v.z = v.z * s.z + t.z;
        v.w = v.w * s.w + t.w;
        y4[i] = v;
    }
}

extern "C" void kernel_launch(void* const* d_in, const int* in_sizes, int n_in,
                              void* d_out, int out_size, void* d_ws, size_t ws_size,
                              hipStream_t stream) {
    const float* feat  = (const float*)d_in[0];
    const int*   src   = (const int*)d_in[1];
    const int*   dst   = (const int*)d_in[2];
    const float* W     = (const float*)d_in[3];
    const float* b     = (const float*)d_in[4];
    const float* RW    = (const float*)d_in[5];
    const float* rb    = (const float*)d_in[6];
    const float* gamma = (const float*)d_in[7];
    const float* beta  = (const float*)d_in[8];

    int N = in_sizes[0] / KDIM;
    int E = in_sizes[1];
    float* out = (float*)d_out;
    int nbuck = (N + 255) >> 8;   // assumes N <= 131072

    // workspace layout
    char* wsb = (char*)d_ws;
    unsigned short* hb = (unsigned short*)wsb;             wsb += (size_t)N * NCOL * 2;
    uint2* pairs    = (uint2*)wsb;                         wsb += (size_t)E * 8;
    int*   ssrc     = (int*)wsb;                           wsb += (size_t)E * 4;
    int*   row_start= (int*)wsb;                           wsb += (size_t)(N + 1) * 4;
    int*   outcnt   = (int*)wsb;                           wsb += (size_t)N * 4;
    float* stats    = (float*)wsb;                         wsb += 256 * 4;
    int*   bcnt     = (int*)wsb;                           wsb += NB * 4;
    int*   bbase    = (int*)wsb;                           wsb += NB * 4;
    int*   bcur     = (int*)wsb;

    // zero outcnt | stats | bcnt (contiguous)
    hipMemsetAsync(outcnt, 0, ((size_t)N + 256 + NB) * 4, stream);

    coarse_hist<<<1024, 256, 0, stream>>>(src, dst, outcnt, bcnt, E);
    bucket_scan<<<1, 256, 0, stream>>>(bcnt, bbase, bcur, row_start, N, E);
    matmul_mfma<<<512, 256, 0, stream>>>(feat, W, RW, rb, outcnt, hb, out, N);
    partition_kernel<<<(E + CH - 1) / CH, 256, 0, stream>>>(src, dst, bcur, pairs, E);
    fine_kernel<<<nbuck, 256, 0, stream>>>(pairs, bbase, row_start, ssrc, E, nbuck, N);
    gather_kernel<<<2048, 256, 0, stream>>>(row_start, ssrc, (const unsigned int*)hb, b, out, stats, N);
    bnparam_kernel<<<1, 64, 0, stream>>>(gamma, beta, stats, 1.0f / (float)N);
    apply_kernel<<<2048, 256, 0, stream>>>(out, stats, (N * NCOL) / 4);
}

// Round 7
// 287.269 us; speedup vs baseline: 1.0263x; 1.0263x over previous
//
#include <hip/hip_runtime.h>
#include <hip/hip_fp16.h>

#define NCOL 64
#define KDIM 128
#define NB 512          // max coarse buckets (dst>>8, N<=131072)
#define CH 2048         // edges per partition chunk

typedef short bf16x8 __attribute__((ext_vector_type(8)));
typedef float f32x4 __attribute__((ext_vector_type(4)));

__device__ __forceinline__ unsigned short f2bf(float f) {
    unsigned int u = __float_as_uint(f);
    return (unsigned short)((u + 0x7fffu + ((u >> 16) & 1u)) >> 16);
}
// fp8 e5m2 = top byte of fp16, round-to-nearest-even
__device__ __forceinline__ unsigned int f2e5(float v) {
    unsigned short h = __half_as_ushort(__float2half(v));
    return ((unsigned int)h + 0x7Fu + ((h >> 8) & 1u)) >> 8;
}
__device__ __forceinline__ float e52f(unsigned int byte) {
    return __half2float(__ushort_as_half((unsigned short)(byte << 8)));
}

// ---------------- K1: coarse bucket hist (LDS) + outcnt hist ----------------
__global__ __launch_bounds__(256) void coarse_hist(const int* __restrict__ src,
                                                   const int* __restrict__ dst,
                                                   int* __restrict__ outcnt,
                                                   int* __restrict__ bcnt, int E) {
    __shared__ int lh[NB];
    int tid = threadIdx.x;
    for (int i = tid; i < NB; i += 256) lh[i] = 0;
    __syncthreads();
    int i = blockIdx.x * blockDim.x + tid;
    int stride = gridDim.x * blockDim.x;
    for (int e = i; e < E; e += stride) {
        atomicAdd(&outcnt[src[e]], 1);
        atomicAdd(&lh[dst[e] >> 8], 1);
    }
    __syncthreads();
    for (int k = tid; k < NB; k += 256) {
        int c = lh[k];
        if (c) atomicAdd(&bcnt[k], c);
    }
}

// ---------------- K2: scan bucket counts -> bbase, bcur ----------------
__global__ __launch_bounds__(256) void bucket_scan(const int* __restrict__ bcnt,
                                                   int* __restrict__ bbase, int* __restrict__ bcur,
                                                   int* __restrict__ row_start, int N, int E) {
    __shared__ int wsum[8];
    int tid = threadIdx.x, lane = tid & 63, wv = tid >> 6;
    int a = bcnt[tid], b = bcnt[tid + 256];
    int ia = a, ib = b;
#pragma unroll
    for (int off = 1; off < 64; off <<= 1) {
        int t = __shfl_up(ia, off); if (lane >= off) ia += t;
        int u = __shfl_up(ib, off); if (lane >= off) ib += u;
    }
    if (lane == 63) { wsum[wv] = ia; wsum[4 + wv] = ib; }
    __syncthreads();
    if (tid == 0) { int run = 0; for (int i = 0; i < 8; ++i) { int t = wsum[i]; wsum[i] = run; run += t; } }
    __syncthreads();
    int ea = wsum[wv] + ia - a;
    int eb = wsum[4 + wv] + ib - b;
    bbase[tid] = ea; bcur[tid] = ea;
    bbase[tid + 256] = eb; bcur[tid + 256] = eb;
    if (tid == 0) row_start[N] = E;
}

// ---------------- K3: partition edges into coarse buckets (coalesced writes) ----------------
__global__ __launch_bounds__(256) void partition_kernel(
    const int* __restrict__ src, const int* __restrict__ dst,
    int* __restrict__ bcur, uint2* __restrict__ pairs, int E) {
    __shared__ int hist[NB];
    __shared__ int lbase[NB];
    __shared__ int gbase[NB];
    __shared__ int lcur[NB];
    __shared__ uint2 sp[CH];   // 16 KB
    __shared__ int wsum[8];

    int tid = threadIdx.x, lane = tid & 63, wv = tid >> 6;
    int c0 = blockIdx.x * CH;
    int cnt = min(CH, E - c0);

    for (int i = tid; i < NB; i += 256) hist[i] = 0;
    __syncthreads();
    for (int i = tid; i < cnt; i += 256)
        atomicAdd(&hist[dst[c0 + i] >> 8], 1);
    __syncthreads();

    // exclusive scan of hist[0..511] with 256 threads
    {
        int a = hist[tid], b = hist[tid + 256];
        int ia = a, ib = b;
#pragma unroll
        for (int off = 1; off < 64; off <<= 1) {
            int t = __shfl_up(ia, off); if (lane >= off) ia += t;
            int u = __shfl_up(ib, off); if (lane >= off) ib += u;
        }
        if (lane == 63) { wsum[wv] = ia; wsum[4 + wv] = ib; }
        __syncthreads();
        if (tid == 0) { int run = 0; for (int i = 0; i < 8; ++i) { int t = wsum[i]; wsum[i] = run; run += t; } }
        __syncthreads();
        lbase[tid] = wsum[wv] + ia - a;
        lbase[tid + 256] = wsum[4 + wv] + ib - b;
    }
    __syncthreads();

    // reserve global space per bucket; init local cursors
    for (int k = tid; k < NB; k += 256) {
        int c = hist[k];
        gbase[k] = c ? atomicAdd(&bcur[k], c) : 0;
        lcur[k] = lbase[k];
    }
    __syncthreads();

    // rescatter chunk into bucket-ordered LDS (re-read global, L2-hot)
    for (int i = tid; i < cnt; i += 256) {
        int s = src[c0 + i], d = dst[c0 + i];
        int p = atomicAdd(&lcur[d >> 8], 1);
        sp[p] = make_uint2((unsigned)s, (unsigned)d);
    }
    __syncthreads();

    // linear write-out: consecutive i within a bucket -> consecutive global addrs
    for (int i = tid; i < cnt; i += 256) {
        uint2 p = sp[i];
        int k = (int)(p.y >> 8);
        pairs[gbase[k] + (i - lbase[k])] = p;
    }
}

// ---------------- K4: fine counting sort within bucket -> ssrc + row_start ----------------
__global__ __launch_bounds__(256) void fine_kernel(
    const uint2* __restrict__ pairs, const int* __restrict__ bbase,
    int* __restrict__ row_start, int* __restrict__ ssrc, int E, int nbuck, int N) {
    __shared__ int hist[256];
    __shared__ int cur[256];
    __shared__ int wsum[4];
    int k = blockIdx.x;
    int tid = threadIdx.x, lane = tid & 63, wv = tid >> 6;
    int b0 = bbase[k];
    int b1 = (k + 1 < nbuck) ? bbase[k + 1] : E;

    hist[tid] = 0;
    __syncthreads();
    for (int i = b0 + tid; i < b1; i += 256)
        atomicAdd(&hist[pairs[i].y & 255], 1);
    __syncthreads();

    // exclusive scan of 256
    int x = hist[tid], inc = x;
#pragma unroll
    for (int off = 1; off < 64; off <<= 1) {
        int t = __shfl_up(inc, off); if (lane >= off) inc += t;
    }
    if (lane == 63) wsum[wv] = inc;
    __syncthreads();
    if (tid == 0) { int run = 0; for (int i = 0; i < 4; ++i) { int t = wsum[i]; wsum[i] = run; run += t; } }
    __syncthreads();
    int excl = wsum[wv] + inc - x;

    int d = (k << 8) + tid;
    if (d < N) row_start[d] = b0 + excl;
    cur[tid] = b0 + excl;
    __syncthreads();

    for (int i = b0 + tid; i < b1; i += 256) {
        uint2 p = pairs[i];
        int pos = atomicAdd(&cur[p.y & 255], 1);
        ssrc[pos] = (int)p.x;
    }
}

// ---------------- K5: MFMA dual GEMM; h stored fp8 e5m2 column-strided ----------------
// hb8[row*16 + c16] dword packs cols {c16, 16+c16, 32+c16, 48+c16} (byte ct = col ct*16+c16).
__global__ __launch_bounds__(256) void matmul_mfma(
    const float* __restrict__ feat, const float* __restrict__ W,
    const float* __restrict__ RW, const float* __restrict__ res_b,
    const int* __restrict__ outcnt,
    unsigned int* __restrict__ hb8, float* __restrict__ y, int N) {
    __shared__ bf16x8 Bf[2048];   // 32 KB
    int tid = threadIdx.x;
    for (int idx = tid; idx < 2048; idx += 256) {
        int mat = idx >> 10;
        int kc = (idx >> 8) & 3;
        int ct = (idx >> 6) & 3;
        int l = idx & 63;
        const float* Wp = mat ? RW : W;
        int kbase = kc * 32 + (l >> 4) * 8;
        int col = ct * 16 + (l & 15);
        bf16x8 t;
#pragma unroll
        for (int j = 0; j < 8; ++j)
            t[j] = (short)f2bf(Wp[(size_t)(kbase + j) * NCOL + col]);
        Bf[idx] = t;
    }
    __syncthreads();

    int lane = tid & 63;
    int wid = tid >> 6;
    int wave = blockIdx.x * 4 + wid;
    int nwaves = gridDim.x * 4;
    int ntiles = (N + 15) >> 4;
    int c16 = lane & 15, kg = lane >> 4;

    float rbv[4];
#pragma unroll
    for (int ct = 0; ct < 4; ++ct) rbv[ct] = res_b[ct * 16 + c16];

    for (int tile = wave; tile < ntiles; tile += nwaves) {
        int tb = tile << 4;
        f32x4 acch[4], accr[4];
#pragma unroll
        for (int ct = 0; ct < 4; ++ct) {
            acch[ct] = (f32x4){0.f, 0.f, 0.f, 0.f};
            accr[ct] = (f32x4){0.f, 0.f, 0.f, 0.f};
        }

        int arow = tb + c16; if (arow >= N) arow = N - 1;
        const float* fp = feat + (size_t)arow * KDIM + kg * 8;
#pragma unroll
        for (int kc = 0; kc < 4; ++kc) {
            float4 a0 = *(const float4*)(fp + kc * 32);
            float4 a1 = *(const float4*)(fp + kc * 32 + 4);
            bf16x8 af;
            af[0] = (short)f2bf(a0.x); af[1] = (short)f2bf(a0.y);
            af[2] = (short)f2bf(a0.z); af[3] = (short)f2bf(a0.w);
            af[4] = (short)f2bf(a1.x); af[5] = (short)f2bf(a1.y);
            af[6] = (short)f2bf(a1.z); af[7] = (short)f2bf(a1.w);
#pragma unroll
            for (int ct = 0; ct < 4; ++ct) {
                acch[ct] = __builtin_amdgcn_mfma_f32_16x16x32_bf16(
                    af, Bf[(kc * 4 + ct) * 64 + lane], acch[ct], 0, 0, 0);
                accr[ct] = __builtin_amdgcn_mfma_f32_16x16x32_bf16(
                    af, Bf[1024 + (kc * 4 + ct) * 64 + lane], accr[ct], 0, 0, 0);
            }
        }

        float nrm[4];
#pragma unroll
        for (int r = 0; r < 4; ++r) {
            int rw = tb + kg * 4 + r; if (rw >= N) rw = N - 1;
            nrm[r] = rsqrtf(fmaxf((float)outcnt[rw], 1.0f));
        }
#pragma unroll
        for (int r = 0; r < 4; ++r) {
            int row = tb + kg * 4 + r;
            if (row < N) {
                unsigned int p = 0;
#pragma unroll
                for (int ct = 0; ct < 4; ++ct) {
                    p |= (f2e5(acch[ct][r] * nrm[r]) & 0xFFu) << (8 * ct);
                    y[(size_t)row * NCOL + ct * 16 + c16] = fmaxf(accr[ct][r] + rbv[ct], 0.0f);
                }
                hb8[(size_t)row * 16 + c16] = p;
            }
        }
    }
}

// ---------------- K6: gather, fp8 rows. wave = 4 edges x 16 lanes ----------------
// lane: e4 = lane>>4 (edge in group), dw = lane&15 (dword of 64B row).
// dword dw holds cols {16j+dw}. 4x unroll -> 16 edges (4 row-loads) in flight.
__global__ __launch_bounds__(256) void gather_kernel(
    const int* __restrict__ row_start, const int* __restrict__ ssrc,
    const unsigned int* __restrict__ hb8, const float* __restrict__ b,
    float* __restrict__ y, float* __restrict__ stats, int N) {
    int tid = threadIdx.x, lane = tid & 63, wid = tid >> 6;
    int e4 = lane >> 4;
    int dw = lane & 15;
    int wave = blockIdx.x * 4 + wid;
    int nwaves = gridDim.x * 4;

    float bc[4];
#pragma unroll
    for (int j = 0; j < 4; ++j) bc[j] = b[16 * j + dw];

    float bnsum[4] = {0.f, 0.f, 0.f, 0.f};
    float bnsq[4] = {0.f, 0.f, 0.f, 0.f};

    for (int d = wave; d < N; d += nwaves) {
        int s0 = row_start[d], s1 = row_start[d + 1];
        float a0 = 0.f, a1 = 0.f, a2 = 0.f, a3 = 0.f;

        int base = s0;
        for (; base + 16 <= s1; base += 16) {
            int i0 = ssrc[base + e4];
            int i1 = ssrc[base + 4 + e4];
            int i2 = ssrc[base + 8 + e4];
            int i3 = ssrc[base + 12 + e4];
            unsigned int v0 = hb8[(size_t)i0 * 16 + dw];
            unsigned int v1 = hb8[(size_t)i1 * 16 + dw];
            unsigned int v2 = hb8[(size_t)i2 * 16 + dw];
            unsigned int v3 = hb8[(size_t)i3 * 16 + dw];
            a0 += e52f(v0 & 0xFF); a1 += e52f((v0 >> 8) & 0xFF); a2 += e52f((v0 >> 16) & 0xFF); a3 += e52f(v0 >> 24);
            a0 += e52f(v1 & 0xFF); a1 += e52f((v1 >> 8) & 0xFF); a2 += e52f((v1 >> 16) & 0xFF); a3 += e52f(v1 >> 24);
            a0 += e52f(v2 & 0xFF); a1 += e52f((v2 >> 8) & 0xFF); a2 += e52f((v2 >> 16) & 0xFF); a3 += e52f(v2 >> 24);
            a0 += e52f(v3 & 0xFF); a1 += e52f((v3 >> 8) & 0xFF); a2 += e52f((v3 >> 16) & 0xFF); a3 += e52f(v3 >> 24);
        }
        for (; base < s1; base += 4) {
            int e = base + e4;
            unsigned int v = (e < s1) ? hb8[(size_t)ssrc[e] * 16 + dw] : 0u;
            a0 += e52f(v & 0xFF); a1 += e52f((v >> 8) & 0xFF); a2 += e52f((v >> 16) & 0xFF); a3 += e52f(v >> 24);
        }

        // reduce across the 4 edge slots (lane bits 4,5)
        a0 += __shfl_xor(a0, 16); a1 += __shfl_xor(a1, 16);
        a2 += __shfl_xor(a2, 16); a3 += __shfl_xor(a3, 16);
        a0 += __shfl_xor(a0, 32); a1 += __shfl_xor(a1, 32);
        a2 += __shfl_xor(a2, 32); a3 += __shfl_xor(a3, 32);

        if (e4 == 0) {
            float nd = rsqrtf(fmaxf((float)(s1 - s0), 1.0f));
            float av[4] = {a0, a1, a2, a3};
#pragma unroll
            for (int j = 0; j < 4; ++j) {
                float* yp = &y[(size_t)d * NCOL + 16 * j + dw];
                float v = fmaxf(av[j] * nd + bc[j], 0.f) + *yp;
                *yp = v;
                bnsum[j] += v;
                bnsq[j] += v * v;
            }
        }
    }

    __shared__ float bnred[4][128];
    if (e4 == 0) {
#pragma unroll
        for (int j = 0; j < 4; ++j) {
            bnred[wid][16 * j + dw] = bnsum[j];
            bnred[wid][64 + 16 * j + dw] = bnsq[j];
        }
    }
    __syncthreads();
    if (tid < 128) {
        float v = bnred[0][tid] + bnred[1][tid] + bnred[2][tid] + bnred[3][tid];
        unsafeAtomicAdd(&stats[tid], v);
    }
}

// ---------------- K7: BN scale/shift ----------------
__global__ void bnparam_kernel(const float* __restrict__ gamma, const float* __restrict__ beta,
                               float* __restrict__ stats, float invN) {
    int c = threadIdx.x;
    float mean = stats[c] * invN;
    float var = stats[64 + c] * invN - mean * mean;
    float s = gamma[c] * rsqrtf(var + 1e-5f);
    stats[128 + c] = s;
    stats[192 + c] = beta[c] - mean * s;
}

// ---------------- K8: BN apply (in place, float4) ----------------
__global__ __launch_bounds__(256) void apply_kernel(float* __restrict__ y,
                                                    const float* __restrict__ stats, int total4) {
    int i = blockIdx.x * blockDim.x + threadIdx.x;
    int stride = gridDim.x * blockDim.x;
    float4* y4 = (float4*)y;
    for (; i < total4; i += stride) {
        float4 v = y4[i];
        int cbase = (i & 15) << 2;
        float4 s = *(const float4*)&stats[128 + cbase];
        float4 t = *(const float4*)&stats[192 + cbase];
        v.x = v.x * s.x + t.x;
        v.y = v.y * s.y + t.y;
        v.z = v.z * s.z + t.z;
        v.w = v.w * s.w + t.w;
        y4[i] = v;
    }
}

extern "C" void kernel_launch(void* const* d_in, const int* in_sizes, int n_in,
                              void* d_out, int out_size, void* d_ws, size_t ws_size,
                              hipStream_t stream) {
    const float* feat  = (const float*)d_in[0];
    const int*   src   = (const int*)d_in[1];
    const int*   dst   = (const int*)d_in[2];
    const float* W     = (const float*)d_in[3];
    const float* b     = (const float*)d_in[4];
    const float* RW    = (const float*)d_in[5];
    const float* rb    = (const float*)d_in[6];
    const float* gamma = (const float*)d_in[7];
    const float* beta  = (const float*)d_in[8];

    int N = in_sizes[0] / KDIM;
    int E = in_sizes[1];
    float* out = (float*)d_out;
    int nbuck = (N + 255) >> 8;   // assumes N <= 131072

    // workspace layout
    char* wsb = (char*)d_ws;
    unsigned int* hb8 = (unsigned int*)wsb;                wsb += (size_t)N * 16 * 4;
    uint2* pairs    = (uint2*)wsb;                         wsb += (size_t)E * 8;
    int*   ssrc     = (int*)wsb;                           wsb += (size_t)E * 4;
    int*   row_start= (int*)wsb;                           wsb += (size_t)(N + 1) * 4;
    int*   outcnt   = (int*)wsb;                           wsb += (size_t)N * 4;
    float* stats    = (float*)wsb;                         wsb += 256 * 4;
    int*   bcnt     = (int*)wsb;                           wsb += NB * 4;
    int*   bbase    = (int*)wsb;                           wsb += NB * 4;
    int*   bcur     = (int*)wsb;

    // zero outcnt | stats | bcnt (contiguous)
    hipMemsetAsync(outcnt, 0, ((size_t)N + 256 + NB) * 4, stream);

    coarse_hist<<<1024, 256, 0, stream>>>(src, dst, outcnt, bcnt, E);
    bucket_scan<<<1, 256, 0, stream>>>(bcnt, bbase, bcur, row_start, N, E);
    matmul_mfma<<<512, 256, 0, stream>>>(feat, W, RW, rb, outcnt, hb8, out, N);
    partition_kernel<<<(E + CH - 1) / CH, 256, 0, stream>>>(src, dst, bcur, pairs, E);
    fine_kernel<<<nbuck, 256, 0, stream>>>(pairs, bbase, row_start, ssrc, E, nbuck, N);
    gather_kernel<<<2048, 256, 0, stream>>>(row_start, ssrc, hb8, b, out, stats, N);
    bnparam_kernel<<<1, 64, 0, stream>>>(gamma, beta, stats, 1.0f / (float)N);
    apply_kernel<<<2048, 256, 0, stream>>>(out, stats, (N * NCOL) / 4);
}